// Round 8
// baseline (1652.204 us; speedup 1.0000x reference)
//
#include <hip/hip_runtime.h>
#include <hip/hip_fp16.h>

#define DIM     192
#define NHEADS  6
#define WSZ     7
#define SHIFT   3
#define TOK     49
#define HW      224
#define NWIN    8192

typedef _Float16 half_t;
typedef _Float16 half8 __attribute__((ext_vector_type(8)));
typedef float    f32x4 __attribute__((ext_vector_type(4)));

#define WQKV_HALFS  (6*96*192)      // 110592: [head][96 rows: q0-31,k32-63,v64-95][192 k] linear
#define WPROJ_HALFS (6*192*32)      // 36864:  [head][192 ch][32 k] linear

// ---------------- weight prep: fp32 -> f16, packed linear ----------------
__global__ __launch_bounds__(256) void prep_weights(const float* __restrict__ qkv_w,
                                                    const float* __restrict__ proj_w,
                                                    half_t* __restrict__ wp) {
  int e = blockIdx.x * 256 + threadIdx.x;
  if (e < WQKV_HALFS) {
    int h  = e / 18432;
    int r1 = e % 18432;
    int r  = r1 / 192;
    int kk = r1 % 192;
    int sect = r >> 5;
    int chl  = r & 31;
    wp[e] = (half_t)qkv_w[(sect*192 + h*32 + chl)*192 + kk];
  } else {
    int e2 = e - WQKV_HALFS;
    if (e2 < WPROJ_HALFS) {
      int h  = e2 / 6144;
      int rr = (e2 >> 5) % 192;
      int kl = e2 & 31;
      wp[WQKV_HALFS + e2] = (half_t)proj_w[rr*192 + h*32 + kl];
    }
  }
}

// ---------------- LDS layout (bytes), total 39936 ----------------
// phase 1: s_x [49][200] half = 19600 @ 0        (dead after A-frag reg read)
// phase 2: s_q  @     0 : [52][40] half = 4160
//          s_k  @  4160 : [52][40] half = 4160
//          s_vt @  8320 : [32][64] half = 4096   (V transposed, 16B-chunk XOR swizzle)
//          s_aoh@ 12416 : [52][40] half = 4160
//          s_p  @ 16576 : [64][72] half = 9216   (normalized P)
// phase 3: s_out @ 0 : [192][52] f32 = 39936 (overlay)
#define SMEM_BYTES 39936

// __launch_bounds__ 2nd arg empirically sets VGPR cap = 2048/(arg * waves_per_block):
//   (512,4) -> cap 64 (r5/r6: pinned 64 VGPR + ~1.4 GB spill traffic)
//   (512,6) -> cap 40 (r4: 40 VGPR + ~4.4 GB spill, 2137 us)
// (512,2) -> cap 128: natural demand ~100 fits spill-free. Runtime occupancy
// follows actual VGPR (~5 waves/SIMD -> 2 blocks/CU), not the bound.
__global__ __launch_bounds__(512, 2) void swin_attn(const float* __restrict__ x,
                                                    const float* __restrict__ qkv_b,
                                                    const float* __restrict__ proj_b,
                                                    const half_t* __restrict__ wp,
                                                    float* __restrict__ out) {
  __shared__ __align__(16) unsigned char smem[SMEM_BYTES];
  half_t* s_x   = (half_t*)smem;              // [49][200]
  half_t* s_q   = (half_t*)smem;              // [52][40]
  half_t* s_k   = (half_t*)(smem + 4160);
  half_t* s_vt  = (half_t*)(smem + 8320);     // [32][64]
  half_t* s_aoh = (half_t*)(smem + 12416);    // [52][40]
  half_t* s_p   = (half_t*)(smem + 16576);    // [64][72]
  float*  s_out = (float*)smem;               // [192][52]

  int bid = blockIdx.x;
  bid = (bid & 7) * 1024 + (bid >> 3);        // XCD-aware swizzle (8192 % 8 == 0)
  int b  = bid >> 10;
  int wh = (bid >> 5) & 31;
  int ww = bid & 31;

  int tid  = threadIdx.x;
  int wave = tid >> 6;
  int lane = tid & 63;
  int lg   = lane >> 4;     // k-group 0..3
  int lr   = lane & 15;     // row/col within tile
  int m    = wave & 3;      // M-tile 0..3
  int nhf  = wave >> 2;     // N-half 0..1
  int mrow0 = m << 4;

  const float* xb = x + (size_t)b * DIM * HW * HW;

  // ---- gather shifted window -> s_x (f16), strength-reduced indexing
  {
    int c = tid / 49;
    int r = tid - c * 49;
    for (int it = 0; it < 19; ++it) {
      if (c < 192) {
        int i = r / 7, j = r - i * 7;
        int hh = wh*WSZ + i + SHIFT; if (hh >= HW) hh -= HW;
        int w2 = ww*WSZ + j + SHIFT; if (w2 >= HW) w2 -= HW;
        s_x[r*200 + c] = (half_t)xb[(size_t)c*(HW*HW) + hh*HW + w2];
      }
      r += 22; c += 10;              // 512 = 10*49 + 22
      if (r >= 49) { r -= 49; ++c; }
    }
  }
  __syncthreads();

  // ---- A fragments to registers, once (each thread: one row, 48 halfs)
  const half8 HZ = {0,0,0,0,0,0,0,0};
  half8 afr[6];
  {
    int arow = mrow0 + lr;
    const half_t* ax = s_x + (arow > 48 ? 48 : arow)*200 + lg*8;
    #pragma unroll
    for (int kc = 0; kc < 3; ++kc)
      #pragma unroll
      for (int ks = 0; ks < 2; ++ks)
        afr[kc*2 + ks] = *(const half8*)(ax + kc*64 + ks*32);
    if (arow > 48) {
      #pragma unroll
      for (int u = 0; u < 6; ++u) afr[u] = HZ;
    }
  }
  __syncthreads();   // s_x dead; its space becomes q/k/vt/aoh

  f32x4 pacc[6];
  #pragma unroll
  for (int n = 0; n < 6; ++n) { pacc[n][0]=0.f; pacc[n][1]=0.f; pacc[n][2]=0.f; pacc[n][3]=0.f; }

  const float qscale = 0.17677669529663687f;   // 32^-0.5
  const half_t* wproj = wp + WQKV_HALFS;

  for (int h = 0; h < NHEADS; ++h) {
    // ---------- qkv GEMM: B-frags direct from global (L2-hot), A from regs. No barriers.
    f32x4 acc[3];
    #pragma unroll
    for (int n = 0; n < 3; ++n) { acc[n][0]=0.f; acc[n][1]=0.f; acc[n][2]=0.f; acc[n][3]=0.f; }
    {
      const half_t* wqh = wp + (size_t)h*18432 + ((nhf*3)*16 + lr)*192 + lg*8;
      #pragma unroll
      for (int kc = 0; kc < 3; ++kc) {
        half8 bfr[6];
        #pragma unroll
        for (int i = 0; i < 3; ++i)
          #pragma unroll
          for (int ks = 0; ks < 2; ++ks)
            bfr[i*2+ks] = *(const half8*)(wqh + i*3072 + kc*64 + ks*32);
        #pragma unroll
        for (int ks = 0; ks < 2; ++ks)
          #pragma unroll
          for (int i = 0; i < 3; ++i)
            acc[i] = __builtin_amdgcn_mfma_f32_16x16x32_f16(afr[kc*2+ks], bfr[i*2+ks], acc[i], 0, 0, 0);
      }
    }
    // ---------- epilogue: q,k row-major [tok][d]; v transposed+swizzled [d][tok]
    #pragma unroll
    for (int i = 0; i < 3; ++i) {
      int nt   = nhf*3 + i;
      int sect = nt >> 1;                 // 0=q 1=k 2=v
      int chl  = (nt & 1)*16 + lr;        // 0..31
      float bia = qkv_b[sect*192 + h*32 + chl];
      if (sect == 0) {
        #pragma unroll
        for (int jj = 0; jj < 4; ++jj) {
          int tok = mrow0 + lg*4 + jj;
          if (tok < 52) s_q[tok*40 + chl] = (half_t)((acc[i][jj] + bia) * qscale);
        }
      } else if (sect == 1) {
        #pragma unroll
        for (int jj = 0; jj < 4; ++jj) {
          int tok = mrow0 + lg*4 + jj;
          if (tok < 52) s_k[tok*40 + chl] = (half_t)(acc[i][jj] + bia);
        }
      } else {
        int tok0 = mrow0 + lg*4;
        union { half_t h4[4]; uint2 u; } pk2;
        #pragma unroll
        for (int jj = 0; jj < 4; ++jj) {
          int tok = tok0 + jj;
          float v = (tok < TOK) ? (acc[i][jj] + bia) : 0.f;   // zero pad tokens
          pk2.h4[jj] = (half_t)v;
        }
        int chunk = (tok0 >> 3) ^ (chl & 7);
        *(uint2*)(s_vt + chl*64 + chunk*8 + (tok0 & 7)) = pk2.u;
      }
    }
    __syncthreads();   // q/k/vt visible

    // ---------- QK^T + softmax: nh==0 waves only; P stored pre-normalized
    if (nhf == 0) {
      f32x4 sacc[4];
      #pragma unroll
      for (int n = 0; n < 4; ++n) { sacc[n][0]=0.f; sacc[n][1]=0.f; sacc[n][2]=0.f; sacc[n][3]=0.f; }
      half8 aq = *(const half8*)(s_q + (mrow0 + lr)*40 + lg*8);
      #pragma unroll
      for (int n = 0; n < 4; ++n) {
        half8 bf = *(const half8*)(s_k + (n*16 + lr)*40 + lg*8);
        sacc[n] = __builtin_amdgcn_mfma_f32_16x16x32_f16(aq, bf, sacc[n], 0, 0, 0);
      }
      if (lr >= 1) {                       // mask cols 49..63
        #pragma unroll
        for (int jj = 0; jj < 4; ++jj) sacc[3][jj] = -1e30f;
      }
      #pragma unroll
      for (int jj = 0; jj < 4; ++jj) {
        float mx = fmaxf(fmaxf(sacc[0][jj], sacc[1][jj]), fmaxf(sacc[2][jj], sacc[3][jj]));
        #pragma unroll
        for (int d = 1; d < 16; d <<= 1) mx = fmaxf(mx, __shfl_xor(mx, d));
        float p[4], ssum = 0.f;
        #pragma unroll
        for (int n = 0; n < 4; ++n) { p[n] = __expf(sacc[n][jj] - mx); ssum += p[n]; }
        #pragma unroll
        for (int d = 1; d < 16; d <<= 1) ssum += __shfl_xor(ssum, d);
        float rl = 1.f / ssum;
        int tok = mrow0 + lg*4 + jj;
        if (tok < 52) {
          #pragma unroll
          for (int n = 0; n < 4; ++n)
            s_p[tok*72 + n*16 + lr] = (half_t)(p[n] * rl);
        }
      }
    }
    __syncthreads();   // P visible

    // ---------- PV: wave's d-tile (d = nhf*16+lr), K=64 toks in 2 steps
    f32x4 oacc;
    oacc[0]=0.f; oacc[1]=0.f; oacc[2]=0.f; oacc[3]=0.f;
    #pragma unroll
    for (int ks = 0; ks < 2; ++ks) {
      half8 a = *(const half8*)(s_p + (mrow0 + lr)*72 + ks*32 + lg*8);
      int d = nhf*16 + lr;
      int chunk = (ks*4 + lg) ^ (d & 7);
      half8 bf = *(const half8*)(s_vt + d*64 + chunk*8);
      oacc = __builtin_amdgcn_mfma_f32_16x16x32_f16(a, bf, oacc, 0, 0, 0);
    }
    #pragma unroll
    for (int jj = 0; jj < 4; ++jj) {
      int tok = mrow0 + lg*4 + jj;
      if (tok < 52) s_aoh[tok*40 + nhf*16 + lr] = (half_t)oacc[jj];
    }
    __syncthreads();   // aoh visible

    // ---------- proj accumulate for this head: B frags direct from global (L2-hot)
    {
      half8 a = *(const half8*)(s_aoh + (mrow0 + lr)*40 + lg*8);
      const half_t* wph = wproj + ((size_t)h*192 + (nhf*6)*16 + lr)*32 + lg*8;
      #pragma unroll
      for (int i2 = 0; i2 < 6; ++i2) {
        half8 bf = *(const half8*)(wph + i2*512);
        pacc[i2] = __builtin_amdgcn_mfma_f32_16x16x32_f16(a, bf, pacc[i2], 0, 0, 0);
      }
    }
  }
  __syncthreads();   // last proj-acc aoh reads done before s_out overlay

  // ---------- bias + transpose to s_out [192][52] f32
  #pragma unroll
  for (int i2 = 0; i2 < 6; ++i2) {
    int ch = (nhf*6 + i2)*16 + lr;
    float bia = proj_b[ch];
    #pragma unroll
    for (int jj = 0; jj < 4; ++jj) {
      int tok = mrow0 + lg*4 + jj;
      if (tok < TOK) s_out[ch*52 + tok] = pacc[i2][jj] + bia;
    }
  }
  __syncthreads();

  // ---------- scatter with inverse roll, strength-reduced indexing
  float* ob = out + (size_t)b * DIM * HW * HW;
  {
    int c = tid / 49;
    int r = tid - c * 49;
    for (int it = 0; it < 19; ++it) {
      if (c < 192) {
        int i = r / 7, j = r - i * 7;
        int hh = wh*WSZ + i + SHIFT; if (hh >= HW) hh -= HW;
        int w2 = ww*WSZ + j + SHIFT; if (w2 >= HW) w2 -= HW;
        ob[(size_t)c*(HW*HW) + hh*HW + w2] = s_out[c*52 + r];
      }
      r += 22; c += 10;
      if (r >= 49) { r -= 49; ++c; }
    }
  }
}

extern "C" void kernel_launch(void* const* d_in, const int* in_sizes, int n_in,
                              void* d_out, int out_size, void* d_ws, size_t ws_size,
                              hipStream_t stream) {
  const float* x      = (const float*)d_in[0];
  const float* qkv_w  = (const float*)d_in[1];
  const float* qkv_b  = (const float*)d_in[2];
  const float* proj_w = (const float*)d_in[3];
  const float* proj_b = (const float*)d_in[4];
  half_t* wpk = (half_t*)d_ws;   // uses 294912 bytes of d_ws

  prep_weights<<<576, 256, 0, stream>>>(qkv_w, proj_w, wpk);
  swin_attn<<<NWIN, 512, 0, stream>>>(x, qkv_b, proj_b, wpk, (float*)d_out);
}

// Round 11
// 1538.000 us; speedup vs baseline: 1.0743x; 1.0743x over previous
//
#include <hip/hip_runtime.h>
#include <hip/hip_fp16.h>

#define HW   224
#define NWIN 8192
#define TOK  49

typedef _Float16 half_t;
typedef _Float16 half8 __attribute__((ext_vector_type(8)));
typedef float    f32x4 __attribute__((ext_vector_type(4)));

#define WQKV_HALFS  (576*192)
#define WPROJ_HALFS (192*192)
#define W_BYTES     ((WQKV_HALFS + WPROJ_HALFS)*2)   // 294912

// ---------- weight prep: fp32 -> f16, layouts identical row-major ----------
__global__ __launch_bounds__(256) void prep_weights(const float* __restrict__ qkv_w,
                                                    const float* __restrict__ proj_w,
                                                    half_t* __restrict__ wp) {
  int e = blockIdx.x*256 + threadIdx.x;
  if (e < WQKV_HALFS) wp[e] = (half_t)qkv_w[e];
  else if (e < WQKV_HALFS + WPROJ_HALFS) wp[e] = (half_t)proj_w[e - WQKV_HALFS];
}

// ---------- K1: qkv GEMM with fused shifted-window gather ----------
// M = ntok (chunk tokens), N = 576 (6 col-blocks of 96), K = 192 (3 chunks of 64).
// q (scaled) and k -> qk[tok][384] token-major f16; v -> vt[win*6+head][32 d][64 keys]
// (transposed, keys 49..63 left unwritten -> masked in K2).
// (256,4): VGPR cap 128 (empirical cap model = 2048/(arg*waves)); natural ~110.
__global__ __launch_bounds__(256, 4) void qkv_gemm(const float* __restrict__ x,
    const float* __restrict__ qkv_b, const half_t* __restrict__ wqkv,
    half_t* __restrict__ qk, half_t* __restrict__ vt, int win_base, int ntok) {
  __shared__ __align__(16) half_t s_a[128*64];   // [tok][64k], 16B-chunk XOR swizzle
  __shared__ __align__(16) half_t s_b[96*64];    // [n][64k], same swizzle
  int bid = blockIdx.x;
  int nb  = bid % 6;
  int mb  = bid / 6;
  int tid = threadIdx.x;
  int wave = tid >> 6, lane = tid & 63, lg = lane >> 4, lr = lane & 15;
  int wm = wave >> 1, wn = wave & 1;             // 2M x 2N waves; wave tile 64x48

  // per-thread gather source (one token, 32 channels)
  int tokl = tid & 127;
  int kq   = tid >> 7;                            // 0..1
  int tok_g = mb*128 + tokl; if (tok_g >= ntok) tok_g = ntok - 1;
  int wrel = tok_g/49;
  int r    = tok_g - wrel*49;
  int win  = win_base + wrel;
  int b    = win >> 10, wh = (win >> 5) & 31, ww = win & 31;
  int i = r/7, j = r - i*7;
  int hh = wh*7 + i + 3; if (hh >= HW) hh -= HW;
  int w2 = ww*7 + j + 3; if (w2 >= HW) w2 -= HW;
  const float* px = x + (size_t)b*192*50176 + hh*224 + w2;

  const float qscale = 0.17677669529663687f;     // 32^-0.5
  f32x4 acc[4][3];
  #pragma unroll
  for (int mt = 0; mt < 4; ++mt)
    #pragma unroll
    for (int nt = 0; nt < 3; ++nt) { acc[mt][nt][0]=0.f; acc[mt][nt][1]=0.f; acc[mt][nt][2]=0.f; acc[mt][nt][3]=0.f; }

  for (int kc = 0; kc < 3; ++kc) {
    if (kc) __syncthreads();
    // stage A: thread covers channels kq*32..+32 of its token (strided gather)
    #pragma unroll
    for (int cc = 0; cc < 4; ++cc) {
      half8 t;
      #pragma unroll
      for (int u = 0; u < 8; ++u)
        t[u] = (half_t)px[(size_t)(kc*64 + kq*32 + cc*8 + u)*50176];
      *(half8*)(s_a + tokl*64 + (((kq*4 + cc) ^ (tokl & 7))*8)) = t;
    }
    // stage B: 768 16B chunks, 3 per thread, coalesced
    #pragma unroll
    for (int s = 0; s < 3; ++s) {
      int ci = tid + 256*s;
      int row = ci >> 3, c = ci & 7;
      half8 t = *(const half8*)(wqkv + (size_t)(nb*96 + row)*192 + kc*64 + c*8);
      *(half8*)(s_b + row*64 + ((c ^ (row & 7))*8)) = t;
    }
    __syncthreads();
    #pragma unroll
    for (int ks = 0; ks < 2; ++ks) {
      half8 af[4], bf[3];
      #pragma unroll
      for (int mt = 0; mt < 4; ++mt)
        af[mt] = *(const half8*)(s_a + (wm*64 + mt*16 + lr)*64 + (((ks*4 + lg) ^ (lr & 7))*8));
      #pragma unroll
      for (int nt = 0; nt < 3; ++nt)
        bf[nt] = *(const half8*)(s_b + (wn*48 + nt*16 + lr)*64 + (((ks*4 + lg) ^ (lr & 7))*8));
      #pragma unroll
      for (int mt = 0; mt < 4; ++mt)
        #pragma unroll
        for (int nt = 0; nt < 3; ++nt)
          acc[mt][nt] = __builtin_amdgcn_mfma_f32_16x16x32_f16(af[mt], bf[nt], acc[mt][nt], 0, 0, 0);
    }
  }
  // C write
  int colb = nb*96 + wn*48;
  #pragma unroll
  for (int nt = 0; nt < 3; ++nt) {
    int ch = colb + nt*16 + lr;                   // 0..576, qkv_w row index
    float bia = qkv_b[ch];
    #pragma unroll
    for (int mt = 0; mt < 4; ++mt) {
      #pragma unroll
      for (int jj = 0; jj < 4; ++jj) {
        int tl = mb*128 + wm*64 + mt*16 + lg*4 + jj;
        if (tl < ntok) {
          float v = acc[mt][nt][jj] + bia;
          if (ch < 192)      qk[(size_t)tl*384 + ch] = (half_t)(v * qscale);
          else if (ch < 384) qk[(size_t)tl*384 + ch] = (half_t)v;
          else {
            int cv = ch - 384, head = cv >> 5, d = cv & 31;
            int wr = tl/49, rr2 = tl - wr*49;
            vt[(size_t)(wr*6 + head)*2048 + d*64 + rr2] = (half_t)v;
          }
        }
      }
    }
  }
}

// ---------- K2: attention, one wave per head-window, zero barriers ----------
// q,k,v fragments direct from global (streams); P via 2.3KB wave-private LDS;
// output overwrites q section in place (rows >=49 of q only feed discarded rows).
__global__ __launch_bounds__(256, 4) void attn(half_t* __restrict__ qk,
    const half_t* __restrict__ vt, int nwh) {
  __shared__ __align__(16) half_t s_p[4][16*72];
  int wave = threadIdx.x >> 6, lane = threadIdx.x & 63, lg = lane >> 4, lr = lane & 15;
  int whd = blockIdx.x*4 + wave;
  if (whd >= nwh) return;
  int win = whd/6, h = whd - win*6;
  half_t* qbase = qk + (size_t)win*49*384 + h*32;
  const half_t* kbase = qbase + 192;
  const half_t* vb = vt + (size_t)whd*2048;
  half_t* sp = &s_p[wave][0];
  const half8 HZ = {0,0,0,0,0,0,0,0};
  for (int mt = 0; mt < 4; ++mt) {
    half8 aq = *(const half8*)(qbase + (size_t)(mt*16 + lr)*384 + lg*8);
    f32x4 sacc[4];
    #pragma unroll
    for (int nt = 0; nt < 4; ++nt) {
      half8 bk = *(const half8*)(kbase + (size_t)(nt*16 + lr)*384 + lg*8);
      f32x4 z = {0.f, 0.f, 0.f, 0.f};
      sacc[nt] = __builtin_amdgcn_mfma_f32_16x16x32_f16(aq, bk, z, 0, 0, 0);
    }
    if (lr >= 1) { sacc[3][0]=-1e30f; sacc[3][1]=-1e30f; sacc[3][2]=-1e30f; sacc[3][3]=-1e30f; }
    #pragma unroll
    for (int jj = 0; jj < 4; ++jj) {
      float mx = fmaxf(fmaxf(sacc[0][jj], sacc[1][jj]), fmaxf(sacc[2][jj], sacc[3][jj]));
      #pragma unroll
      for (int d2 = 1; d2 < 16; d2 <<= 1) mx = fmaxf(mx, __shfl_xor(mx, d2));
      float p0 = __expf(sacc[0][jj]-mx), p1 = __expf(sacc[1][jj]-mx),
            p2 = __expf(sacc[2][jj]-mx), p3 = __expf(sacc[3][jj]-mx);
      float ss = p0 + p1 + p2 + p3;
      #pragma unroll
      for (int d2 = 1; d2 < 16; d2 <<= 1) ss += __shfl_xor(ss, d2);
      float rl = 1.f/ss;
      int row = lg*4 + jj;
      sp[row*72      + lr] = (half_t)(p0*rl);
      sp[row*72 + 16 + lr] = (half_t)(p1*rl);
      sp[row*72 + 32 + lr] = (half_t)(p2*rl);
      sp[row*72 + 48 + lr] = (half_t)(p3*rl);
    }
    f32x4 o0 = {0.f,0.f,0.f,0.f}, o1 = {0.f,0.f,0.f,0.f};
    #pragma unroll
    for (int ks = 0; ks < 2; ++ks) {
      half8 pa  = *(const half8*)(sp + lr*72 + ks*32 + lg*8);
      half8 bv0 = *(const half8*)(vb + lr*64        + ks*32 + lg*8);
      half8 bv1 = *(const half8*)(vb + (16 + lr)*64 + ks*32 + lg*8);
      if (ks == 1) {                       // keys 32..63: zero keys>=49 (pads unwritten -> may be non-finite)
        if (lg == 3) { bv0 = HZ; bv1 = HZ; }
        else if (lg == 2) {
          half8 z0 = HZ; z0[0] = bv0[0]; bv0 = z0;
          half8 z1 = HZ; z1[0] = bv1[0]; bv1 = z1;
        }
      }
      o0 = __builtin_amdgcn_mfma_f32_16x16x32_f16(pa, bv0, o0, 0, 0, 0);
      o1 = __builtin_amdgcn_mfma_f32_16x16x32_f16(pa, bv1, o1, 0, 0, 0);
    }
    #pragma unroll
    for (int jj = 0; jj < 4; ++jj) {
      int tok = mt*16 + lg*4 + jj;
      if (tok < TOK) {
        qbase[(size_t)tok*384 + lr]      = (half_t)o0[jj];
        qbase[(size_t)tok*384 + 16 + lr] = (half_t)o1[jj];
      }
    }
  }
}

// ---------- K3: proj GEMM per window + scatter with inverse roll ----------
__global__ __launch_bounds__(256, 4) void proj_scatter(const half_t* __restrict__ qk,
    const half_t* __restrict__ wproj, const float* __restrict__ proj_b,
    float* __restrict__ out, int win_base) {
  __shared__ __align__(16) float s_out[192*52];   // 39936 B
  int tid = threadIdx.x;
  int wave = tid >> 6, lane = tid & 63, lg = lane >> 4, lr = lane & 15;
  int win_rel = blockIdx.x;
  const half_t* ab = qk + ((size_t)win_rel*49 + wave*16 + lr)*384;  // o section, ch 0..192
  half8 af[6];
  #pragma unroll
  for (int ks = 0; ks < 6; ++ks) af[ks] = *(const half8*)(ab + ks*32 + lg*8);
  f32x4 acc[12];
  #pragma unroll
  for (int nt = 0; nt < 12; ++nt) { acc[nt][0]=0.f; acc[nt][1]=0.f; acc[nt][2]=0.f; acc[nt][3]=0.f; }
  #pragma unroll
  for (int ks = 0; ks < 6; ++ks)
    #pragma unroll
    for (int nt = 0; nt < 12; ++nt) {
      half8 bf = *(const half8*)(wproj + (size_t)(nt*16 + lr)*192 + ks*32 + lg*8);
      acc[nt] = __builtin_amdgcn_mfma_f32_16x16x32_f16(af[ks], bf, acc[nt], 0, 0, 0);
    }
  #pragma unroll
  for (int nt = 0; nt < 12; ++nt) {
    int ch = nt*16 + lr;
    float bia = proj_b[ch];
    #pragma unroll
    for (int jj = 0; jj < 4; ++jj) {
      int tok = wave*16 + lg*4 + jj;
      if (tok < TOK) s_out[ch*52 + tok] = acc[nt][jj] + bia;
    }
  }
  __syncthreads();
  int win = win_base + win_rel;
  int b = win >> 10, wh = (win >> 5) & 31, ww = win & 31;
  float* ob = out + (size_t)b*192*50176;
  int c = tid/49, r2 = tid - (tid/49)*49;
  for (int it = 0; it < 37; ++it) {               // 256 = 5*49 + 11
    if (c < 192) {
      int i = r2/7, j = r2 - i*7;
      int hh = wh*7 + i + 3; if (hh >= HW) hh -= HW;
      int w2 = ww*7 + j + 3; if (w2 >= HW) w2 -= HW;
      ob[(size_t)c*50176 + hh*224 + w2] = s_out[c*52 + r2];
    }
    r2 += 11; c += 5;
    if (r2 >= 49) { r2 -= 49; ++c; }
  }
}

extern "C" void kernel_launch(void* const* d_in, const int* in_sizes, int n_in,
                              void* d_out, int out_size, void* d_ws, size_t ws_size,
                              hipStream_t stream) {
  const float* x      = (const float*)d_in[0];
  const float* qkv_w  = (const float*)d_in[1];
  const float* qkv_b  = (const float*)d_in[2];
  const float* proj_w = (const float*)d_in[3];
  const float* proj_b = (const float*)d_in[4];
  half_t* wp = (half_t*)d_ws;
  // per-window scratch: qk 49*384*2 + v 6*2048*2 = 62208 B; chunk windows to fit ws_size
  const size_t perwin = (size_t)49*384*2 + (size_t)6*2048*2;
  size_t avail = (ws_size > (size_t)W_BYTES + 256) ? ws_size - W_BYTES - 256 : 0;
  long cap = (long)(avail / perwin);
  if (cap > NWIN) cap = NWIN;
  if (cap < 1) cap = 1;
  half_t* qk = (half_t*)((char*)d_ws + W_BYTES);
  half_t* vt = qk + (size_t)cap*49*384;

  prep_weights<<<(WQKV_HALFS + WPROJ_HALFS + 255)/256, 256, 0, stream>>>(qkv_w, proj_w, wp);
  const half_t* wqkv  = wp;
  const half_t* wproj = wp + WQKV_HALFS;

  for (long w0 = 0; w0 < NWIN; w0 += cap) {
    int cnt  = (int)((NWIN - w0 < cap) ? (NWIN - w0) : cap);
    int ntok = cnt*49;
    int mb   = (ntok + 127)/128;
    qkv_gemm<<<mb*6, 256, 0, stream>>>(x, qkv_b, wqkv, qk, vt, (int)w0, ntok);
    attn<<<(cnt*6 + 3)/4, 256, 0, stream>>>(qk, vt, cnt*6);
    proj_scatter<<<cnt, 256, 0, stream>>>(qk, wproj, proj_b, (float*)d_out, (int)w0);
  }
}

// Round 12
// 1520.269 us; speedup vs baseline: 1.0868x; 1.0117x over previous
//
#include <hip/hip_runtime.h>
#include <hip/hip_fp16.h>

#define HW   224
#define NWIN 8192
#define TOK  49
#define NTOKG 401408            // 8192 windows * 49

typedef _Float16 half_t;
typedef _Float16 half8 __attribute__((ext_vector_type(8)));
typedef float    f32x4 __attribute__((ext_vector_type(4)));

#define WQKV_HALFS  (576*192)
#define WPROJ_HALFS (192*192)
#define W_BYTES     ((WQKV_HALFS + WPROJ_HALFS)*2)   // 294912
#define PACKED_BYTES ((size_t)NTOKG*192*2)           // 154,140,672

// ---------- weight prep: fp32 -> f16, layouts identical row-major ----------
__global__ __launch_bounds__(256) void prep_weights(const float* __restrict__ qkv_w,
                                                    const float* __restrict__ proj_w,
                                                    half_t* __restrict__ wp) {
  int e = blockIdx.x*256 + threadIdx.x;
  if (e < WQKV_HALFS) wp[e] = (half_t)qkv_w[e];
  else if (e < WQKV_HALFS + WPROJ_HALFS) wp[e] = (half_t)proj_w[e - WQKV_HALFS];
}

// ---------- K0: im2col — coalesced pixel-linear read, token-major f16 write ----------
// x[b][c][hh][w2] -> packed[tok][c], tok = window-major order with shift roll folded in.
// Reads: lane = consecutive pixel -> perfect coalescing, 1x fetch of 308 MB.
// Writes: 4B scattered within a 96KB/block footprint -> L2 write-combines.
__global__ __launch_bounds__(256) void im2col(const float* __restrict__ x,
                                              half_t* __restrict__ packed) {
  int blk = blockIdx.x;                 // 8 b * 196 ptiles
  int b = blk / 196, pt = blk - b*196;
  int p = pt*256 + threadIdx.x;         // 0..50175
  int hh = p / 224, w2 = p - hh*224;
  int hs0 = hh + 221; if (hs0 >= 224) hs0 -= 224;   // (hh-3) mod 224
  int ws0 = w2 + 221; if (ws0 >= 224) ws0 -= 224;
  int wh = hs0 / 7, i = hs0 - wh*7;
  int ww = ws0 / 7, j = ws0 - ww*7;
  int tok = (b*1024 + wh*32 + ww)*49 + i*7 + j;     // global token
  const float* px = x + (size_t)b*192*50176 + p;
  half_t* pout = packed + (size_t)tok*192;
  #pragma unroll 4
  for (int c = 0; c < 192; c += 2) {
    float v0 = px[(size_t)c*50176];
    float v1 = px[(size_t)(c+1)*50176];
    union { half_t h2[2]; unsigned u; } pk;
    pk.h2[0] = (half_t)v0; pk.h2[1] = (half_t)v1;
    *(unsigned*)(pout + c) = pk.u;
  }
}

// ---------- K1: qkv GEMM from packed A ----------
// M-tile 256 x N-tile 96 (nb 0..5), K=192 in 3 chunks of 64. 512 thr = 8 waves (4wm x 2wn).
// LDS: s_a [256][64] 32KB + s_b [96][64] 12KB, 16B-chunk XOR swizzle. (512,2): cap 128.
__global__ __launch_bounds__(512, 2) void qkv_gemm(const half_t* __restrict__ packed,
    const float* __restrict__ qkv_b, const half_t* __restrict__ wqkv,
    half_t* __restrict__ qk, half_t* __restrict__ vt, int tok_base, int ntok) {
  __shared__ __align__(16) half_t s_a[256*64];
  __shared__ __align__(16) half_t s_b[96*64];
  int bid = blockIdx.x;
  int nb  = bid % 6;
  int mb  = bid / 6;
  int tid = threadIdx.x;
  int wave = tid >> 6, lane = tid & 63, lg = lane >> 4, lr = lane & 15;
  int wm = wave >> 1, wn = wave & 1;     // wave tile 64 x 48

  const float qscale = 0.17677669529663687f;   // 32^-0.5
  f32x4 acc[4][3];
  #pragma unroll
  for (int mt = 0; mt < 4; ++mt)
    #pragma unroll
    for (int nt = 0; nt < 3; ++nt) { acc[mt][nt][0]=0.f; acc[mt][nt][1]=0.f; acc[mt][nt][2]=0.f; acc[mt][nt][3]=0.f; }

  for (int kc = 0; kc < 3; ++kc) {
    if (kc) __syncthreads();
    // stage A: 2048 16B chunks, 4/thread, coalesced 128B row-chunks (128B-aligned: 384=3*128)
    #pragma unroll
    for (int s = 0; s < 4; ++s) {
      int ci  = tid + 512*s;
      int row = ci >> 3, cs = ci & 7;
      int grow = tok_base + mb*256 + row;
      if (grow >= NTOKG) grow = NTOKG - 1;
      half8 t = *(const half8*)(packed + (size_t)grow*192 + kc*64 + cs*8);
      *(half8*)(s_a + row*64 + ((cs ^ (row & 7))*8)) = t;
    }
    // stage B: 768 16B chunks
    {
      int ci = tid;
      int row = ci >> 3, c = ci & 7;
      half8 t = *(const half8*)(wqkv + (size_t)(nb*96 + row)*192 + kc*64 + c*8);
      *(half8*)(s_b + row*64 + ((c ^ (row & 7))*8)) = t;
      if (tid < 256) {
        int ci2 = 512 + tid;
        int row2 = ci2 >> 3, c2 = ci2 & 7;
        half8 t2 = *(const half8*)(wqkv + (size_t)(nb*96 + row2)*192 + kc*64 + c2*8);
        *(half8*)(s_b + row2*64 + ((c2 ^ (row2 & 7))*8)) = t2;
      }
    }
    __syncthreads();
    #pragma unroll
    for (int ks = 0; ks < 2; ++ks) {
      half8 af[4], bf[3];
      #pragma unroll
      for (int mt = 0; mt < 4; ++mt) {
        int row = wm*64 + mt*16 + lr;
        af[mt] = *(const half8*)(s_a + row*64 + (((ks*4 + lg) ^ (row & 7))*8));
      }
      #pragma unroll
      for (int nt = 0; nt < 3; ++nt) {
        int row = wn*48 + nt*16 + lr;
        bf[nt] = *(const half8*)(s_b + row*64 + (((ks*4 + lg) ^ (row & 7))*8));
      }
      #pragma unroll
      for (int mt = 0; mt < 4; ++mt)
        #pragma unroll
        for (int nt = 0; nt < 3; ++nt)
          acc[mt][nt] = __builtin_amdgcn_mfma_f32_16x16x32_f16(af[mt], bf[nt], acc[mt][nt], 0, 0, 0);
    }
  }
  // C write (chunk-local token index)
  int colb = nb*96 + wn*48;
  #pragma unroll
  for (int nt = 0; nt < 3; ++nt) {
    int ch = colb + nt*16 + lr;
    float bia = qkv_b[ch];
    #pragma unroll
    for (int mt = 0; mt < 4; ++mt) {
      #pragma unroll
      for (int jj = 0; jj < 4; ++jj) {
        int tl = mb*256 + wm*64 + mt*16 + lg*4 + jj;
        if (tl < ntok) {
          float v = acc[mt][nt][jj] + bia;
          if (ch < 192)      qk[(size_t)tl*384 + ch] = (half_t)(v * qscale);
          else if (ch < 384) qk[(size_t)tl*384 + ch] = (half_t)v;
          else {
            int cv = ch - 384, head = cv >> 5, d = cv & 31;
            int wr = tl/49, rr2 = tl - wr*49;
            vt[(size_t)(wr*6 + head)*2048 + d*64 + rr2] = (half_t)v;
          }
        }
      }
    }
  }
}

// ---------- K2: attention, one wave per head-window, zero barriers ----------
__global__ __launch_bounds__(256, 4) void attn(half_t* __restrict__ qk,
    const half_t* __restrict__ vt, int nwh) {
  __shared__ __align__(16) half_t s_p[4][16*72];
  int wave = threadIdx.x >> 6, lane = threadIdx.x & 63, lg = lane >> 4, lr = lane & 15;
  int whd = blockIdx.x*4 + wave;
  if (whd >= nwh) return;
  int win = whd/6, h = whd - win*6;
  half_t* qbase = qk + (size_t)win*49*384 + h*32;
  const half_t* kbase = qbase + 192;
  const half_t* vb = vt + (size_t)whd*2048;
  half_t* sp = &s_p[wave][0];
  const half8 HZ = {0,0,0,0,0,0,0,0};
  for (int mt = 0; mt < 4; ++mt) {
    half8 aq = *(const half8*)(qbase + (size_t)(mt*16 + lr)*384 + lg*8);
    f32x4 sacc[4];
    #pragma unroll
    for (int nt = 0; nt < 4; ++nt) {
      half8 bk = *(const half8*)(kbase + (size_t)(nt*16 + lr)*384 + lg*8);
      f32x4 z = {0.f, 0.f, 0.f, 0.f};
      sacc[nt] = __builtin_amdgcn_mfma_f32_16x16x32_f16(aq, bk, z, 0, 0, 0);
    }
    if (lr >= 1) { sacc[3][0]=-1e30f; sacc[3][1]=-1e30f; sacc[3][2]=-1e30f; sacc[3][3]=-1e30f; }
    #pragma unroll
    for (int jj = 0; jj < 4; ++jj) {
      float mx = fmaxf(fmaxf(sacc[0][jj], sacc[1][jj]), fmaxf(sacc[2][jj], sacc[3][jj]));
      #pragma unroll
      for (int d2 = 1; d2 < 16; d2 <<= 1) mx = fmaxf(mx, __shfl_xor(mx, d2));
      float p0 = __expf(sacc[0][jj]-mx), p1 = __expf(sacc[1][jj]-mx),
            p2 = __expf(sacc[2][jj]-mx), p3 = __expf(sacc[3][jj]-mx);
      float ss = p0 + p1 + p2 + p3;
      #pragma unroll
      for (int d2 = 1; d2 < 16; d2 <<= 1) ss += __shfl_xor(ss, d2);
      float rl = 1.f/ss;
      int row = lg*4 + jj;
      sp[row*72      + lr] = (half_t)(p0*rl);
      sp[row*72 + 16 + lr] = (half_t)(p1*rl);
      sp[row*72 + 32 + lr] = (half_t)(p2*rl);
      sp[row*72 + 48 + lr] = (half_t)(p3*rl);
    }
    f32x4 o0 = {0.f,0.f,0.f,0.f}, o1 = {0.f,0.f,0.f,0.f};
    #pragma unroll
    for (int ks = 0; ks < 2; ++ks) {
      half8 pa  = *(const half8*)(sp + lr*72 + ks*32 + lg*8);
      half8 bv0 = *(const half8*)(vb + lr*64        + ks*32 + lg*8);
      half8 bv1 = *(const half8*)(vb + (16 + lr)*64 + ks*32 + lg*8);
      if (ks == 1) {                       // zero keys >= 49 (unwritten pads)
        if (lg == 3) { bv0 = HZ; bv1 = HZ; }
        else if (lg == 2) {
          half8 z0 = HZ; z0[0] = bv0[0]; bv0 = z0;
          half8 z1 = HZ; z1[0] = bv1[0]; bv1 = z1;
        }
      }
      o0 = __builtin_amdgcn_mfma_f32_16x16x32_f16(pa, bv0, o0, 0, 0, 0);
      o1 = __builtin_amdgcn_mfma_f32_16x16x32_f16(pa, bv1, o1, 0, 0, 0);
    }
    #pragma unroll
    for (int jj = 0; jj < 4; ++jj) {
      int tok = mt*16 + lg*4 + jj;
      if (tok < TOK) {
        qbase[(size_t)tok*384 + lr]      = (half_t)o0[jj];
        qbase[(size_t)tok*384 + 16 + lr] = (half_t)o1[jj];
      }
    }
  }
}

// ---------- K3: proj GEMM per window + scatter with inverse roll ----------
__global__ __launch_bounds__(256, 4) void proj_scatter(const half_t* __restrict__ qk,
    const half_t* __restrict__ wproj, const float* __restrict__ proj_b,
    float* __restrict__ out, int win_base) {
  __shared__ __align__(16) float s_out[192*52];   // 39936 B
  int tid = threadIdx.x;
  int wave = tid >> 6, lane = tid & 63, lg = lane >> 4, lr = lane & 15;
  int win_rel = blockIdx.x;
  const half_t* ab = qk + ((size_t)win_rel*49 + wave*16 + lr)*384;  // o section, ch 0..192
  half8 af[6];
  #pragma unroll
  for (int ks = 0; ks < 6; ++ks) af[ks] = *(const half8*)(ab + ks*32 + lg*8);
  f32x4 acc[12];
  #pragma unroll
  for (int nt = 0; nt < 12; ++nt) { acc[nt][0]=0.f; acc[nt][1]=0.f; acc[nt][2]=0.f; acc[nt][3]=0.f; }
  #pragma unroll
  for (int ks = 0; ks < 6; ++ks)
    #pragma unroll
    for (int nt = 0; nt < 12; ++nt) {
      half8 bf = *(const half8*)(wproj + (size_t)(nt*16 + lr)*192 + ks*32 + lg*8);
      acc[nt] = __builtin_amdgcn_mfma_f32_16x16x32_f16(af[ks], bf, acc[nt], 0, 0, 0);
    }
  #pragma unroll
  for (int nt = 0; nt < 12; ++nt) {
    int ch = nt*16 + lr;
    float bia = proj_b[ch];
    #pragma unroll
    for (int jj = 0; jj < 4; ++jj) {
      int tok = wave*16 + lg*4 + jj;
      if (tok < TOK) s_out[ch*52 + tok] = acc[nt][jj] + bia;
    }
  }
  __syncthreads();
  int win = win_base + win_rel;
  int b = win >> 10, wh = (win >> 5) & 31, ww = win & 31;
  float* ob = out + (size_t)b*192*50176;
  int c = tid/49, r2 = tid - (tid/49)*49;
  for (int it = 0; it < 37; ++it) {               // 256 = 5*49 + 11
    if (c < 192) {
      int i = r2/7, j = r2 - i*7;
      int hh = wh*7 + i + 3; if (hh >= HW) hh -= HW;
      int w2 = ww*7 + j + 3; if (w2 >= HW) w2 -= HW;
      ob[(size_t)c*50176 + hh*224 + w2] = s_out[c*52 + r2];
    }
    r2 += 11; c += 5;
    if (r2 >= 49) { r2 -= 49; ++c; }
  }
}

extern "C" void kernel_launch(void* const* d_in, const int* in_sizes, int n_in,
                              void* d_out, int out_size, void* d_ws, size_t ws_size,
                              hipStream_t stream) {
  const float* x      = (const float*)d_in[0];
  const float* qkv_w  = (const float*)d_in[1];
  const float* qkv_b  = (const float*)d_in[2];
  const float* proj_w = (const float*)d_in[3];
  const float* proj_b = (const float*)d_in[4];
  half_t* wp     = (half_t*)d_ws;
  half_t* packed = (half_t*)((char*)d_ws + W_BYTES);
  // remaining ws after weights + packed A: chunk qk/vt (perwin = 62208 B)
  const size_t fixed = (size_t)W_BYTES + PACKED_BYTES + 256;
  const size_t perwin = (size_t)49*384*2 + (size_t)6*2048*2;
  size_t avail = (ws_size > fixed) ? ws_size - fixed : 0;
  long cap = (long)(avail / perwin);
  if (cap > NWIN) cap = NWIN;
  if (cap < 1) cap = 1;
  half_t* qk = packed + (size_t)NTOKG*192;
  half_t* vt = qk + (size_t)cap*49*384;

  prep_weights<<<(WQKV_HALFS + WPROJ_HALFS + 255)/256, 256, 0, stream>>>(qkv_w, proj_w, wp);
  im2col<<<8*196, 256, 0, stream>>>(x, packed);
  const half_t* wqkv  = wp;
  const half_t* wproj = wp + WQKV_HALFS;

  for (long w0 = 0; w0 < NWIN; w0 += cap) {
    int cnt  = (int)((NWIN - w0 < cap) ? (NWIN - w0) : cap);
    int ntok = cnt*49;
    int mb   = (ntok + 255)/256;
    qkv_gemm<<<mb*6, 512, 0, stream>>>(packed, qkv_b, wqkv, qk, vt, (int)(w0*49), ntok);
    attn<<<(cnt*6 + 3)/4, 256, 0, stream>>>(qk, vt, cnt*6);
    proj_scatter<<<cnt, 256, 0, stream>>>(qk, wproj, proj_b, (float*)d_out, (int)w0);
  }
}

// Round 13
// 1112.540 us; speedup vs baseline: 1.4851x; 1.3665x over previous
//
#include <hip/hip_runtime.h>
#include <hip/hip_fp16.h>

#define HW   224
#define NWIN 8192
#define TOK  49

typedef _Float16 half_t;
typedef _Float16 half8 __attribute__((ext_vector_type(8)));
typedef float    f32x4 __attribute__((ext_vector_type(4)));

#define WQKV_HALFS  (576*192)
#define WPROJ_HALFS (192*192)
#define W_BYTES     ((WQKV_HALFS + WPROJ_HALFS)*2)   // 294912

// ---------- weight prep: fp32 -> f16, row-major ----------
__global__ __launch_bounds__(256) void prep_weights(const float* __restrict__ qkv_w,
                                                    const float* __restrict__ proj_w,
                                                    half_t* __restrict__ wp) {
  int e = blockIdx.x*256 + threadIdx.x;
  if (e < WQKV_HALFS) wp[e] = (half_t)qkv_w[e];
  else if (e < WQKV_HALFS + WPROJ_HALFS) wp[e] = (half_t)proj_w[e - WQKV_HALFS];
}

// ---------- K1: IMPLICIT qkv GEMM ----------
// A staged straight from pixel-linear x (coalesced 256B loads, LDS transpose via
// per-thread half8 pack -> ds_write_b128; pattern measured 0 bank conflicts r11/12).
// Block: 128 pixels x 192 out-ch (nb: 0=q,1=k,2=v), K=192 in 3 chunks of 64.
// 512 thr = 8 waves (4 wm x 2 wn); wave tile 32 pix x 96 ch; acc 2x6 f32x4 = 48 VGPR.
// C-write computes tok(p) (roll folded) and scatters to qk/vt.
__global__ __launch_bounds__(512, 2) void qkv_gemm(const float* __restrict__ x,
    const float* __restrict__ qkv_b, const half_t* __restrict__ wqkv,
    half_t* __restrict__ qk, half_t* __restrict__ vt, int b0, int cb) {
  __shared__ __align__(16) half_t s_a[128*64];   // [pix][64c], 16B-chunk XOR swizzle
  __shared__ __align__(16) half_t s_b[192*64];   // [ch][64c], same swizzle
  int bid = blockIdx.x;
  int nb  = bid % 3;
  int mb  = bid / 3;                  // 0 .. cb*392-1 (392 tiles of 128 pixels per image)
  int tid = threadIdx.x;
  int wave = tid >> 6, lane = tid & 63, lg = lane >> 4, lr = lane & 15;
  int wm = wave >> 1, wn = wave & 1;

  int ib    = mb / 392;               // image within chunk
  int bimg  = b0 + ib;
  int pimg0 = (mb - ib*392) * 128;    // pixel base within image
  const float* xb = x + (size_t)bimg*192*50176;

  int apix = tid & 127;               // A-load: lane-consecutive pixels
  int acg0 = tid >> 7;                // c-group 0..3 (+4 on 2nd pair)

  f32x4 acc[2][6];
  #pragma unroll
  for (int mt = 0; mt < 2; ++mt)
    #pragma unroll
    for (int nt = 0; nt < 6; ++nt) { acc[mt][nt][0]=0.f; acc[mt][nt][1]=0.f; acc[mt][nt][2]=0.f; acc[mt][nt][3]=0.f; }

  for (int kc = 0; kc < 3; ++kc) {
    if (kc) __syncthreads();
    // stage A: 2 x (8 coalesced dword loads -> half8 -> ds_write_b128)
    #pragma unroll
    for (int pr = 0; pr < 2; ++pr) {
      int cg = acg0 + pr*4;
      const float* ps = xb + (size_t)(kc*64 + cg*8)*50176 + pimg0 + apix;
      half8 t;
      #pragma unroll
      for (int u = 0; u < 8; ++u) t[u] = (half_t)ps[(size_t)u*50176];
      *(half8*)(s_a + apix*64 + ((cg ^ (apix & 7))*8)) = t;
    }
    // stage B: 192 rows x 8 chunks = 1536 half8, 3/thread
    #pragma unroll
    for (int s = 0; s < 3; ++s) {
      int ci = tid + 512*s;
      int row = ci >> 3, cg = ci & 7;
      half8 t = *(const half8*)(wqkv + (size_t)(nb*192 + row)*192 + kc*64 + cg*8);
      *(half8*)(s_b + row*64 + ((cg ^ (row & 7))*8)) = t;
    }
    __syncthreads();
    #pragma unroll
    for (int ks = 0; ks < 2; ++ks) {
      half8 af[2], bf[6];
      #pragma unroll
      for (int mt = 0; mt < 2; ++mt) {
        int rowp = wm*32 + mt*16 + lr;
        af[mt] = *(const half8*)(s_a + rowp*64 + (((ks*4 + lg) ^ (rowp & 7))*8));
      }
      #pragma unroll
      for (int nt = 0; nt < 6; ++nt) {
        int rowc = wn*96 + nt*16 + lr;
        bf[nt] = *(const half8*)(s_b + rowc*64 + (((ks*4 + lg) ^ (rowc & 7))*8));
      }
      #pragma unroll
      for (int mt = 0; mt < 2; ++mt)
        #pragma unroll
        for (int nt = 0; nt < 6; ++nt)
          acc[mt][nt] = __builtin_amdgcn_mfma_f32_16x16x32_f16(af[mt], bf[nt], acc[mt][nt], 0, 0, 0);
    }
  }

  // token map for this thread's 8 output rows (roll + window partition folded)
  int tl8[2][4], vb8[2][4];
  #pragma unroll
  for (int mt = 0; mt < 2; ++mt)
    #pragma unroll
    for (int jj = 0; jj < 4; ++jj) {
      int p  = pimg0 + wm*32 + mt*16 + lg*4 + jj;
      int hh = p / 224, w2 = p - hh*224;
      int hs = hh + 221; if (hs >= 224) hs -= 224;    // (hh-3) mod 224
      int ws0 = w2 + 221; if (ws0 >= 224) ws0 -= 224;
      int wh = hs / 7,  ii = hs - wh*7;
      int ww = ws0 / 7, jw = ws0 - ww*7;
      int winl = ib*1024 + wh*32 + ww;                // chunk-local window
      int key  = ii*7 + jw;
      tl8[mt][jj] = winl*49 + key;
      vb8[mt][jj] = winl*12288 + key;                 // winl*6*2048 + key
    }

  const float qscale = 0.17677669529663687f;          // 32^-0.5
  if (nb == 0) {
    #pragma unroll
    for (int nt = 0; nt < 6; ++nt) {
      int ch = wn*96 + nt*16 + lr;
      float bia = qkv_b[ch];
      #pragma unroll
      for (int mt = 0; mt < 2; ++mt)
        #pragma unroll
        for (int jj = 0; jj < 4; ++jj)
          qk[(size_t)tl8[mt][jj]*384 + ch] = (half_t)((acc[mt][nt][jj] + bia) * qscale);
    }
  } else if (nb == 1) {
    #pragma unroll
    for (int nt = 0; nt < 6; ++nt) {
      int ch = wn*96 + nt*16 + lr;
      float bia = qkv_b[192 + ch];
      #pragma unroll
      for (int mt = 0; mt < 2; ++mt)
        #pragma unroll
        for (int jj = 0; jj < 4; ++jj)
          qk[(size_t)tl8[mt][jj]*384 + 192 + ch] = (half_t)(acc[mt][nt][jj] + bia);
    }
  } else {
    #pragma unroll
    for (int nt = 0; nt < 6; ++nt) {
      int cv = wn*96 + nt*16 + lr;
      int head = cv >> 5, d = cv & 31;
      float bia = qkv_b[384 + cv];
      #pragma unroll
      for (int mt = 0; mt < 2; ++mt)
        #pragma unroll
        for (int jj = 0; jj < 4; ++jj)
          vt[(size_t)vb8[mt][jj] + head*2048 + d*64] = (half_t)(acc[mt][nt][jj] + bia);
    }
  }
}

// ---------- K2: attention, one wave per head-window, zero barriers ----------
__global__ __launch_bounds__(256, 4) void attn(half_t* __restrict__ qk,
    const half_t* __restrict__ vt, int nwh) {
  __shared__ __align__(16) half_t s_p[4][16*72];
  int wave = threadIdx.x >> 6, lane = threadIdx.x & 63, lg = lane >> 4, lr = lane & 15;
  int whd = blockIdx.x*4 + wave;
  if (whd >= nwh) return;
  int win = whd/6, h = whd - win*6;
  half_t* qbase = qk + (size_t)win*49*384 + h*32;
  const half_t* kbase = qbase + 192;
  const half_t* vb = vt + (size_t)whd*2048;
  half_t* sp = &s_p[wave][0];
  const half8 HZ = {0,0,0,0,0,0,0,0};
  for (int mt = 0; mt < 4; ++mt) {
    half8 aq = *(const half8*)(qbase + (size_t)(mt*16 + lr)*384 + lg*8);
    f32x4 sacc[4];
    #pragma unroll
    for (int nt = 0; nt < 4; ++nt) {
      half8 bk = *(const half8*)(kbase + (size_t)(nt*16 + lr)*384 + lg*8);
      f32x4 z = {0.f, 0.f, 0.f, 0.f};
      sacc[nt] = __builtin_amdgcn_mfma_f32_16x16x32_f16(aq, bk, z, 0, 0, 0);
    }
    if (lr >= 1) { sacc[3][0]=-1e30f; sacc[3][1]=-1e30f; sacc[3][2]=-1e30f; sacc[3][3]=-1e30f; }
    #pragma unroll
    for (int jj = 0; jj < 4; ++jj) {
      float mx = fmaxf(fmaxf(sacc[0][jj], sacc[1][jj]), fmaxf(sacc[2][jj], sacc[3][jj]));
      #pragma unroll
      for (int d2 = 1; d2 < 16; d2 <<= 1) mx = fmaxf(mx, __shfl_xor(mx, d2));
      float p0 = __expf(sacc[0][jj]-mx), p1 = __expf(sacc[1][jj]-mx),
            p2 = __expf(sacc[2][jj]-mx), p3 = __expf(sacc[3][jj]-mx);
      float ss = p0 + p1 + p2 + p3;
      #pragma unroll
      for (int d2 = 1; d2 < 16; d2 <<= 1) ss += __shfl_xor(ss, d2);
      float rl = 1.f/ss;
      int row = lg*4 + jj;
      sp[row*72      + lr] = (half_t)(p0*rl);
      sp[row*72 + 16 + lr] = (half_t)(p1*rl);
      sp[row*72 + 32 + lr] = (half_t)(p2*rl);
      sp[row*72 + 48 + lr] = (half_t)(p3*rl);
    }
    f32x4 o0 = {0.f,0.f,0.f,0.f}, o1 = {0.f,0.f,0.f,0.f};
    #pragma unroll
    for (int ks = 0; ks < 2; ++ks) {
      half8 pa  = *(const half8*)(sp + lr*72 + ks*32 + lg*8);
      half8 bv0 = *(const half8*)(vb + lr*64        + ks*32 + lg*8);
      half8 bv1 = *(const half8*)(vb + (16 + lr)*64 + ks*32 + lg*8);
      if (ks == 1) {                       // zero keys >= 49 (unwritten pads)
        if (lg == 3) { bv0 = HZ; bv1 = HZ; }
        else if (lg == 2) {
          half8 z0 = HZ; z0[0] = bv0[0]; bv0 = z0;
          half8 z1 = HZ; z1[0] = bv1[0]; bv1 = z1;
        }
      }
      o0 = __builtin_amdgcn_mfma_f32_16x16x32_f16(pa, bv0, o0, 0, 0, 0);
      o1 = __builtin_amdgcn_mfma_f32_16x16x32_f16(pa, bv1, o1, 0, 0, 0);
    }
    #pragma unroll
    for (int jj = 0; jj < 4; ++jj) {
      int tok = mt*16 + lg*4 + jj;
      if (tok < TOK) {
        qbase[(size_t)tok*384 + lr]      = (half_t)o0[jj];
        qbase[(size_t)tok*384 + 16 + lr] = (half_t)o1[jj];
      }
    }
  }
}

// ---------- K3: proj GEMM per window + scatter with inverse roll ----------
__global__ __launch_bounds__(256, 4) void proj_scatter(const half_t* __restrict__ qk,
    const half_t* __restrict__ wproj, const float* __restrict__ proj_b,
    float* __restrict__ out, int win_base) {
  __shared__ __align__(16) float s_out[192*52];   // 39936 B
  int tid = threadIdx.x;
  int wave = tid >> 6, lane = tid & 63, lg = lane >> 4, lr = lane & 15;
  int win_rel = blockIdx.x;
  const half_t* ab = qk + ((size_t)win_rel*49 + wave*16 + lr)*384;  // o section
  half8 af[6];
  #pragma unroll
  for (int ks = 0; ks < 6; ++ks) af[ks] = *(const half8*)(ab + ks*32 + lg*8);
  f32x4 acc[12];
  #pragma unroll
  for (int nt = 0; nt < 12; ++nt) { acc[nt][0]=0.f; acc[nt][1]=0.f; acc[nt][2]=0.f; acc[nt][3]=0.f; }
  #pragma unroll
  for (int ks = 0; ks < 6; ++ks)
    #pragma unroll
    for (int nt = 0; nt < 12; ++nt) {
      half8 bf = *(const half8*)(wproj + (size_t)(nt*16 + lr)*192 + ks*32 + lg*8);
      acc[nt] = __builtin_amdgcn_mfma_f32_16x16x32_f16(af[ks], bf, acc[nt], 0, 0, 0);
    }
  #pragma unroll
  for (int nt = 0; nt < 12; ++nt) {
    int ch = nt*16 + lr;
    float bia = proj_b[ch];
    #pragma unroll
    for (int jj = 0; jj < 4; ++jj) {
      int tok = wave*16 + lg*4 + jj;
      if (tok < TOK) s_out[ch*52 + tok] = acc[nt][jj] + bia;
    }
  }
  __syncthreads();
  int win = win_base + win_rel;
  int b = win >> 10, wh = (win >> 5) & 31, ww = win & 31;
  float* ob = out + (size_t)b*192*50176;
  int c = tid/49, r2 = tid - (tid/49)*49;
  for (int it = 0; it < 37; ++it) {               // 256 = 5*49 + 11
    if (c < 192) {
      int i = r2/7, j = r2 - i*7;
      int hh = wh*7 + i + 3; if (hh >= HW) hh -= HW;
      int w2 = ww*7 + j + 3; if (w2 >= HW) w2 -= HW;
      ob[(size_t)c*50176 + hh*224 + w2] = s_out[c*52 + r2];
    }
    r2 += 11; c += 5;
    if (r2 >= 49) { r2 -= 49; ++c; }
  }
}

extern "C" void kernel_launch(void* const* d_in, const int* in_sizes, int n_in,
                              void* d_out, int out_size, void* d_ws, size_t ws_size,
                              hipStream_t stream) {
  const float* x      = (const float*)d_in[0];
  const float* qkv_w  = (const float*)d_in[1];
  const float* qkv_b  = (const float*)d_in[2];
  const float* proj_w = (const float*)d_in[3];
  const float* proj_b = (const float*)d_in[4];
  half_t* wp = (half_t*)d_ws;
  // chunk by batch: per-image scratch = qk 1024*49*384*2 + vt 1024*6*2048*2 = 63,700,992 B
  const size_t perb = (size_t)1024*49*384*2 + (size_t)1024*6*2048*2;
  const size_t fixed = (size_t)W_BYTES + 256;
  size_t avail = (ws_size > fixed) ? ws_size - fixed : 0;
  long capb = (long)(avail / perb);
  if (capb > 8) capb = 8;
  if (capb < 1) capb = 1;
  half_t* qk = (half_t*)((char*)d_ws + fixed);
  half_t* vt = qk + (size_t)capb*1024*49*384;

  prep_weights<<<(WQKV_HALFS + WPROJ_HALFS + 255)/256, 256, 0, stream>>>(qkv_w, proj_w, wp);
  const half_t* wqkv  = wp;
  const half_t* wproj = wp + WQKV_HALFS;

  for (long b0 = 0; b0 < 8; b0 += capb) {
    int cb = (int)((8 - b0 < capb) ? (8 - b0) : capb);
    qkv_gemm<<<cb*392*3, 512, 0, stream>>>(x, qkv_b, wqkv, qk, vt, (int)b0, cb);
    attn<<<(cb*6144 + 3)/4, 256, 0, stream>>>(qk, vt, cb*6144);
    proj_scatter<<<cb*1024, 256, 0, stream>>>(qk, wproj, proj_b, (float*)d_out, (int)(b0*1024));
  }
}

// Round 14
// 781.194 us; speedup vs baseline: 2.1150x; 1.4242x over previous
//
#include <hip/hip_runtime.h>
#include <hip/hip_fp16.h>

#define HW   224
#define NWIN 8192
#define TOK  49

typedef _Float16 half_t;
typedef _Float16 half8 __attribute__((ext_vector_type(8)));
typedef float    f32x4 __attribute__((ext_vector_type(4)));

#define WQKV_HALFS  (576*192)
#define WPROJ_HALFS (192*192)
#define W_BYTES     ((WQKV_HALFS + WPROJ_HALFS)*2)   // 294912

// ---------- weight prep: fp32 -> f16, row-major ----------
__global__ __launch_bounds__(256) void prep_weights(const float* __restrict__ qkv_w,
                                                    const float* __restrict__ proj_w,
                                                    half_t* __restrict__ wp) {
  int e = blockIdx.x*256 + threadIdx.x;
  if (e < WQKV_HALFS) wp[e] = (half_t)qkv_w[e];
  else if (e < WQKV_HALFS + WPROJ_HALFS) wp[e] = (half_t)proj_w[e - WQKV_HALFS];
}

// ---------- K1: IMPLICIT qkv GEMM (unchanged from r13) ----------
__global__ __launch_bounds__(512, 2) void qkv_gemm(const float* __restrict__ x,
    const float* __restrict__ qkv_b, const half_t* __restrict__ wqkv,
    half_t* __restrict__ qk, half_t* __restrict__ vt, int b0, int cb) {
  __shared__ __align__(16) half_t s_a[128*64];   // [pix][64c], 16B-chunk XOR swizzle
  __shared__ __align__(16) half_t s_b[192*64];
  int bid = blockIdx.x;
  int nb  = bid % 3;
  int mb  = bid / 3;
  int tid = threadIdx.x;
  int wave = tid >> 6, lane = tid & 63, lg = lane >> 4, lr = lane & 15;
  int wm = wave >> 1, wn = wave & 1;

  int ib    = mb / 392;
  int bimg  = b0 + ib;
  int pimg0 = (mb - ib*392) * 128;
  const float* xb = x + (size_t)bimg*192*50176;

  int apix = tid & 127;
  int acg0 = tid >> 7;

  f32x4 acc[2][6];
  #pragma unroll
  for (int mt = 0; mt < 2; ++mt)
    #pragma unroll
    for (int nt = 0; nt < 6; ++nt) { acc[mt][nt][0]=0.f; acc[mt][nt][1]=0.f; acc[mt][nt][2]=0.f; acc[mt][nt][3]=0.f; }

  for (int kc = 0; kc < 3; ++kc) {
    if (kc) __syncthreads();
    #pragma unroll
    for (int pr = 0; pr < 2; ++pr) {
      int cg = acg0 + pr*4;
      const float* ps = xb + (size_t)(kc*64 + cg*8)*50176 + pimg0 + apix;
      half8 t;
      #pragma unroll
      for (int u = 0; u < 8; ++u) t[u] = (half_t)ps[(size_t)u*50176];
      *(half8*)(s_a + apix*64 + ((cg ^ (apix & 7))*8)) = t;
    }
    #pragma unroll
    for (int s = 0; s < 3; ++s) {
      int ci = tid + 512*s;
      int row = ci >> 3, cg = ci & 7;
      half8 t = *(const half8*)(wqkv + (size_t)(nb*192 + row)*192 + kc*64 + cg*8);
      *(half8*)(s_b + row*64 + ((cg ^ (row & 7))*8)) = t;
    }
    __syncthreads();
    #pragma unroll
    for (int ks = 0; ks < 2; ++ks) {
      half8 af[2], bf[6];
      #pragma unroll
      for (int mt = 0; mt < 2; ++mt) {
        int rowp = wm*32 + mt*16 + lr;
        af[mt] = *(const half8*)(s_a + rowp*64 + (((ks*4 + lg) ^ (rowp & 7))*8));
      }
      #pragma unroll
      for (int nt = 0; nt < 6; ++nt) {
        int rowc = wn*96 + nt*16 + lr;
        bf[nt] = *(const half8*)(s_b + rowc*64 + (((ks*4 + lg) ^ (rowc & 7))*8));
      }
      #pragma unroll
      for (int mt = 0; mt < 2; ++mt)
        #pragma unroll
        for (int nt = 0; nt < 6; ++nt)
          acc[mt][nt] = __builtin_amdgcn_mfma_f32_16x16x32_f16(af[mt], bf[nt], acc[mt][nt], 0, 0, 0);
    }
  }

  int tl8[2][4], vb8[2][4];
  #pragma unroll
  for (int mt = 0; mt < 2; ++mt)
    #pragma unroll
    for (int jj = 0; jj < 4; ++jj) {
      int p  = pimg0 + wm*32 + mt*16 + lg*4 + jj;
      int hh = p / 224, w2 = p - hh*224;
      int hs = hh + 221; if (hs >= 224) hs -= 224;
      int ws0 = w2 + 221; if (ws0 >= 224) ws0 -= 224;
      int wh = hs / 7,  ii = hs - wh*7;
      int ww = ws0 / 7, jw = ws0 - ww*7;
      int winl = ib*1024 + wh*32 + ww;
      int key  = ii*7 + jw;
      tl8[mt][jj] = winl*49 + key;
      vb8[mt][jj] = winl*12288 + key;
    }

  const float qscale = 0.17677669529663687f;
  if (nb == 0) {
    #pragma unroll
    for (int nt = 0; nt < 6; ++nt) {
      int ch = wn*96 + nt*16 + lr;
      float bia = qkv_b[ch];
      #pragma unroll
      for (int mt = 0; mt < 2; ++mt)
        #pragma unroll
        for (int jj = 0; jj < 4; ++jj)
          qk[(size_t)tl8[mt][jj]*384 + ch] = (half_t)((acc[mt][nt][jj] + bia) * qscale);
    }
  } else if (nb == 1) {
    #pragma unroll
    for (int nt = 0; nt < 6; ++nt) {
      int ch = wn*96 + nt*16 + lr;
      float bia = qkv_b[192 + ch];
      #pragma unroll
      for (int mt = 0; mt < 2; ++mt)
        #pragma unroll
        for (int jj = 0; jj < 4; ++jj)
          qk[(size_t)tl8[mt][jj]*384 + 192 + ch] = (half_t)(acc[mt][nt][jj] + bia);
    }
  } else {
    #pragma unroll
    for (int nt = 0; nt < 6; ++nt) {
      int cv = wn*96 + nt*16 + lr;
      int head = cv >> 5, d = cv & 31;
      float bia = qkv_b[384 + cv];
      #pragma unroll
      for (int mt = 0; mt < 2; ++mt)
        #pragma unroll
        for (int jj = 0; jj < 4; ++jj)
          vt[(size_t)vb8[mt][jj] + head*2048 + d*64] = (half_t)(acc[mt][nt][jj] + bia);
    }
  }
}

// ---------- K2: attention, one wave per head-window, zero barriers (unchanged) ----------
__global__ __launch_bounds__(256, 4) void attn(half_t* __restrict__ qk,
    const half_t* __restrict__ vt, int nwh) {
  __shared__ __align__(16) half_t s_p[4][16*72];
  int wave = threadIdx.x >> 6, lane = threadIdx.x & 63, lg = lane >> 4, lr = lane & 15;
  int whd = blockIdx.x*4 + wave;
  if (whd >= nwh) return;
  int win = whd/6, h = whd - win*6;
  half_t* qbase = qk + (size_t)win*49*384 + h*32;
  const half_t* kbase = qbase + 192;
  const half_t* vb = vt + (size_t)whd*2048;
  half_t* sp = &s_p[wave][0];
  const half8 HZ = {0,0,0,0,0,0,0,0};
  for (int mt = 0; mt < 4; ++mt) {
    half8 aq = *(const half8*)(qbase + (size_t)(mt*16 + lr)*384 + lg*8);
    f32x4 sacc[4];
    #pragma unroll
    for (int nt = 0; nt < 4; ++nt) {
      half8 bk = *(const half8*)(kbase + (size_t)(nt*16 + lr)*384 + lg*8);
      f32x4 z = {0.f, 0.f, 0.f, 0.f};
      sacc[nt] = __builtin_amdgcn_mfma_f32_16x16x32_f16(aq, bk, z, 0, 0, 0);
    }
    if (lr >= 1) { sacc[3][0]=-1e30f; sacc[3][1]=-1e30f; sacc[3][2]=-1e30f; sacc[3][3]=-1e30f; }
    #pragma unroll
    for (int jj = 0; jj < 4; ++jj) {
      float mx = fmaxf(fmaxf(sacc[0][jj], sacc[1][jj]), fmaxf(sacc[2][jj], sacc[3][jj]));
      #pragma unroll
      for (int d2 = 1; d2 < 16; d2 <<= 1) mx = fmaxf(mx, __shfl_xor(mx, d2));
      float p0 = __expf(sacc[0][jj]-mx), p1 = __expf(sacc[1][jj]-mx),
            p2 = __expf(sacc[2][jj]-mx), p3 = __expf(sacc[3][jj]-mx);
      float ss = p0 + p1 + p2 + p3;
      #pragma unroll
      for (int d2 = 1; d2 < 16; d2 <<= 1) ss += __shfl_xor(ss, d2);
      float rl = 1.f/ss;
      int row = lg*4 + jj;
      sp[row*72      + lr] = (half_t)(p0*rl);
      sp[row*72 + 16 + lr] = (half_t)(p1*rl);
      sp[row*72 + 32 + lr] = (half_t)(p2*rl);
      sp[row*72 + 48 + lr] = (half_t)(p3*rl);
    }
    f32x4 o0 = {0.f,0.f,0.f,0.f}, o1 = {0.f,0.f,0.f,0.f};
    #pragma unroll
    for (int ks = 0; ks < 2; ++ks) {
      half8 pa  = *(const half8*)(sp + lr*72 + ks*32 + lg*8);
      half8 bv0 = *(const half8*)(vb + lr*64        + ks*32 + lg*8);
      half8 bv1 = *(const half8*)(vb + (16 + lr)*64 + ks*32 + lg*8);
      if (ks == 1) {
        if (lg == 3) { bv0 = HZ; bv1 = HZ; }
        else if (lg == 2) {
          half8 z0 = HZ; z0[0] = bv0[0]; bv0 = z0;
          half8 z1 = HZ; z1[0] = bv1[0]; bv1 = z1;
        }
      }
      o0 = __builtin_amdgcn_mfma_f32_16x16x32_f16(pa, bv0, o0, 0, 0, 0);
      o1 = __builtin_amdgcn_mfma_f32_16x16x32_f16(pa, bv1, o1, 0, 0, 0);
    }
    #pragma unroll
    for (int jj = 0; jj < 4; ++jj) {
      int tok = mt*16 + lg*4 + jj;
      if (tok < TOK) {
        qbase[(size_t)tok*384 + lr]      = (half_t)o0[jj];
        qbase[(size_t)tok*384 + 16 + lr] = (half_t)o1[jj];
      }
    }
  }
}

// ---------- K3: IMPLICIT col2im proj GEMM ----------
// Block: 128 consecutive output pixels x 192 channels, K=192 (o rows) in 3 chunks.
// A gathered from qk o-section via the SAME pixel->token map as K1 (out-roll is
// the inverse of the in-roll); C-write pixel-linear: one float4/lane = dense 64B
// sectors across the wave. No s_out transpose, no scatter.
__global__ __launch_bounds__(512, 2) void proj_col2im(const half_t* __restrict__ qk,
    const half_t* __restrict__ wproj, const float* __restrict__ proj_b,
    float* __restrict__ out, int b0) {
  __shared__ __align__(16) half_t s_a[128*64];
  __shared__ __align__(16) half_t s_b[192*64];
  int bid = blockIdx.x;
  int ib    = bid / 392;
  int bimg  = b0 + ib;
  int pimg0 = (bid - ib*392) * 128;
  int tid = threadIdx.x;
  int wave = tid >> 6, lane = tid & 63, lg = lane >> 4, lr = lane & 15;
  int wm = wave >> 1, wn = wave & 1;

  // staging thread's pixel -> chunk-local token (roll folded; ~15 VALU, once)
  int apix = tid & 127;
  int acg0 = tid >> 7;
  int tl;
  {
    int p  = pimg0 + apix;
    int hh = p / 224, w2 = p - hh*224;
    int hs = hh + 221; if (hs >= 224) hs -= 224;
    int ws0 = w2 + 221; if (ws0 >= 224) ws0 -= 224;
    int wh = hs / 7,  ii = hs - wh*7;
    int ww = ws0 / 7, jw = ws0 - ww*7;
    tl = (ib*1024 + wh*32 + ww)*49 + ii*7 + jw;
  }
  const half_t* ao = qk + (size_t)tl*384;         // o section: ch 0..191

  f32x4 acc[2][6];
  #pragma unroll
  for (int mt = 0; mt < 2; ++mt)
    #pragma unroll
    for (int nt = 0; nt < 6; ++nt) { acc[mt][nt][0]=0.f; acc[mt][nt][1]=0.f; acc[mt][nt][2]=0.f; acc[mt][nt][3]=0.f; }

  for (int kc = 0; kc < 3; ++kc) {
    if (kc) __syncthreads();
    // stage A: 2 x 16B gathered chunks per thread (block footprint 48KB -> L2)
    #pragma unroll
    for (int pr = 0; pr < 2; ++pr) {
      int cg = acg0 + pr*4;
      half8 t = *(const half8*)(ao + kc*64 + cg*8);
      *(half8*)(s_a + apix*64 + ((cg ^ (apix & 7))*8)) = t;
    }
    // stage B: wproj rows (out_ch major), 1536 half8, 3/thread
    #pragma unroll
    for (int s = 0; s < 3; ++s) {
      int ci = tid + 512*s;
      int row = ci >> 3, cg = ci & 7;
      half8 t = *(const half8*)(wproj + (size_t)row*192 + kc*64 + cg*8);
      *(half8*)(s_b + row*64 + ((cg ^ (row & 7))*8)) = t;
    }
    __syncthreads();
    #pragma unroll
    for (int ks = 0; ks < 2; ++ks) {
      half8 af[2], bf[6];
      #pragma unroll
      for (int mt = 0; mt < 2; ++mt) {
        int rowp = wm*32 + mt*16 + lr;
        af[mt] = *(const half8*)(s_a + rowp*64 + (((ks*4 + lg) ^ (rowp & 7))*8));
      }
      #pragma unroll
      for (int nt = 0; nt < 6; ++nt) {
        int rowc = wn*96 + nt*16 + lr;
        bf[nt] = *(const half8*)(s_b + rowc*64 + (((ks*4 + lg) ^ (rowc & 7))*8));
      }
      #pragma unroll
      for (int mt = 0; mt < 2; ++mt)
        #pragma unroll
        for (int nt = 0; nt < 6; ++nt)
          acc[mt][nt] = __builtin_amdgcn_mfma_f32_16x16x32_f16(af[mt], bf[nt], acc[mt][nt], 0, 0, 0);
    }
  }

  // C-write: lane = (ch=wn*96+nt*16+lr, 4 consecutive pixels) -> one float4 store
  float* ob = out + (size_t)bimg*192*50176;
  #pragma unroll
  for (int nt = 0; nt < 6; ++nt) {
    int ch = wn*96 + nt*16 + lr;
    float bia = proj_b[ch];
    #pragma unroll
    for (int mt = 0; mt < 2; ++mt) {
      int p0 = pimg0 + wm*32 + mt*16 + lg*4;
      f32x4 v;
      v[0] = acc[mt][nt][0] + bia; v[1] = acc[mt][nt][1] + bia;
      v[2] = acc[mt][nt][2] + bia; v[3] = acc[mt][nt][3] + bia;
      *(f32x4*)(ob + (size_t)ch*50176 + p0) = v;
    }
  }
}

extern "C" void kernel_launch(void* const* d_in, const int* in_sizes, int n_in,
                              void* d_out, int out_size, void* d_ws, size_t ws_size,
                              hipStream_t stream) {
  const float* x      = (const float*)d_in[0];
  const float* qkv_w  = (const float*)d_in[1];
  const float* qkv_b  = (const float*)d_in[2];
  const float* proj_w = (const float*)d_in[3];
  const float* proj_b = (const float*)d_in[4];
  half_t* wp = (half_t*)d_ws;
  // chunk by batch: per-image scratch = qk 1024*49*384*2 + vt 1024*6*2048*2 = 63,700,992 B
  const size_t perb = (size_t)1024*49*384*2 + (size_t)1024*6*2048*2;
  const size_t fixed = (size_t)W_BYTES + 256;
  size_t avail = (ws_size > fixed) ? ws_size - fixed : 0;
  long capb = (long)(avail / perb);
  if (capb > 8) capb = 8;
  if (capb < 1) capb = 1;
  half_t* qk = (half_t*)((char*)d_ws + fixed);
  half_t* vt = qk + (size_t)capb*1024*49*384;

  prep_weights<<<(WQKV_HALFS + WPROJ_HALFS + 255)/256, 256, 0, stream>>>(qkv_w, proj_w, wp);
  const half_t* wqkv  = wp;
  const half_t* wproj = wp + WQKV_HALFS;

  for (long b0 = 0; b0 < 8; b0 += capb) {
    int cb = (int)((8 - b0 < capb) ? (8 - b0) : capb);
    qkv_gemm<<<cb*392*3, 512, 0, stream>>>(x, qkv_b, wqkv, qk, vt, (int)b0, cb);
    attn<<<(cb*6144 + 3)/4, 256, 0, stream>>>(qk, vt, cb*6144);
    proj_col2im<<<cb*392, 512, 0, stream>>>(qk, wproj, proj_b, (float*)d_out, (int)b0);
  }
}